// Round 8
// baseline (178.853 us; speedup 1.0000x reference)
//
#include <hip/hip_runtime.h>

// LoRA linear, fp32 in/out: out = x @ (W + 2*B@A)^T + b
//   prep:   Weff = bf16(W + 2*B@A) only (2 MiB, 512 blocks, ~5us). R8: the 32 MiB
//           xbf pass (~30us serialized) is gone — gemm stages x fp32 DIRECTLY into
//           LDS via global_load_lds (keeps the deep vmcnt pipeline; no reg-staging,
//           so no R4-latency / R6-spill traps) and converts to bf16 after lgkmcnt(0).
//   gemm256: 256x128x32 2-phase bf16 MFMA GEMM, LDS 80KB/block -> 2 blocks/CU.
//           Wave grid 4M x 2N (A re-read 2x, not 4x: fp32 A doubles LDS bytes).
//           A fp32 [128][32] halves, swizzle c^(r&7) (128B rows, 8 chunks);
//           B bf16 [128][32], R7-verified swizzle c^((r>>1)&3). Counted vmcnt(3)
//           (5 gld16/tile), raw s_barrier, setprio, XCD-chunked blockIdx.
//   Fallback (ws too small): old 128x128 kernel, A staged via fp32 loads + HW cvt.

typedef __bf16 bf16x8 __attribute__((ext_vector_type(8)));
typedef float f32x4 __attribute__((ext_vector_type(4)));
typedef unsigned short ushort8 __attribute__((ext_vector_type(8)));

__device__ __forceinline__ unsigned short f2bf(float f) {
    __bf16 h = (__bf16)f;                       // HW RNE convert
    union { __bf16 b; unsigned short u; } v; v.b = h; return v.u;
}
__device__ __forceinline__ ushort8 cvt8u(f32x4 a, f32x4 b) {
    ushort8 o;
#pragma unroll
    for (int i = 0; i < 4; ++i) { o[i] = f2bf(a[i]); o[i + 4] = f2bf(b[i]); }
    return o;
}
__device__ __forceinline__ bf16x8 cvt8(f32x4 a, f32x4 b) {
    union { ushort8 u; bf16x8 h; } v; v.u = cvt8u(a, b); return v.h;
}
__device__ __forceinline__ void gld16(const void* g, void* l) {
    __builtin_amdgcn_global_load_lds(
        (const __attribute__((address_space(1))) unsigned int*)g,
        (__attribute__((address_space(3))) unsigned int*)l, 16, 0, 0);
}

#define FENCE() asm volatile("" ::: "memory")
#define BARRIER() do { FENCE(); __builtin_amdgcn_s_barrier(); FENCE(); } while (0)

// ---------------- prep: Weff fold only (512 blocks) ----------------
__global__ __launch_bounds__(256) void prep(
    const float* __restrict__ W, const float* __restrict__ A,
    const float* __restrict__ B, unsigned short* __restrict__ Weff)
{
    const int idx = blockIdx.x * 256 + threadIdx.x;
    const int o  = idx >> 7;
    const int kc = (idx & 127) << 3;
    float br[16];
#pragma unroll
    for (int r = 0; r < 16; ++r) br[r] = 2.0f * B[o * 16 + r];
    float acc[8];
    const float* wrow = W + (size_t)o * 1024 + kc;
#pragma unroll
    for (int j = 0; j < 8; ++j) acc[j] = wrow[j];
#pragma unroll
    for (int r = 0; r < 16; ++r) {
        const float* arow = A + r * 1024 + kc;
#pragma unroll
        for (int j = 0; j < 8; ++j) acc[j] += br[r] * arow[j];
    }
    ushort8 o8;
#pragma unroll
    for (int j = 0; j < 8; ++j) o8[j] = f2bf(acc[j]);
    *(ushort8*)(Weff + (size_t)o * 1024 + kc) = o8;
}

// ---------------- gemm256: 256x128x32, fp32-A-in-LDS, 2 blocks/CU ----------------
// Geometry: BM=256, BN=128, BK=32, 512 thr = 8 waves (4M x 2N: wr=w&3, wc=w>>2).
//   Per-wave out 64x64: m-frags f=4*mt+wr (mt=0..3; mt<2 -> A-half0, mt>=2 -> half1),
//   n-frags cols (wc+2*nt)*16 (nt=0..3).
// LDS 80 KiB: 2 bufs x {A0 f32 [128][32] @0, A1 f32 @16384, B bf16 [128][32]
//   @32768} bytes; buf stride 40960. 2 blocks/CU = 163840 B = full pool.
// Swizzle A (128B rows, 8 x 16B chunks): pos p holds src chunk p^(r&7). Reader
//   (16 lanes, quad fixed): pos (2q)^(r16&7) covers all 8 bank groups 2x -> free.
//   Write: chunk id g (0..1023), row g>>3, pos g&7 -> linear dest, pre-swz source.
// Swizzle B: R7-verified c^((r>>1)&3) on 64B rows (conflicts=0 measured).
// Pipeline (tile j): p0 reads A-half0 (4 f32x4) + fb[0..3]; stages A1(j+1)->nxt.
//   p1 reads A-half1; stages A0(j+2)->cur + B(j+2)->cur; checkpoint.
//   cvt fp32->bf16 happens AFTER lgkmcnt(0)+sched_barrier, inside setprio region.
// vmcnt ledger (5 gld16/tile: A0x2,A1x2,B): at p1 checkpoint outstanding =
//   [A0(j+1)x2,B(j+1)](j-1 p1) + [A1(j+1)x2](j p0) + [A0(j+2)x2,B(j+2)](j p1) = 8
//   -> vmcnt(3) retires 5 = all of tile j+1. Peel: j==30 -> vmcnt(0) (only
//   A1(31)x2... none: stages stop j>=30 for A0/B, j>=31 for A1 -> at j=30 p1
//   outstanding = tile-31's 5 loads -> vmcnt(0) drains them. j=31: nothing.
__global__ __launch_bounds__(512, 4) void gemm256(
    const float* __restrict__ Xf,              // fp32 x [M][1024]
    const unsigned short* __restrict__ Wt,     // bf16 Weff [1024][1024]
    const float* __restrict__ bias,            // fp32 [1024]
    float* __restrict__ out)                   // fp32 [M][1024]
{
    extern __shared__ __align__(16) char lds[];   // 81920 B

    const int t    = threadIdx.x;
    const int lane = t & 63;
    const int w    = t >> 6;
    const int wr   = w & 3;         // 0..3 (M)
    const int wc   = w >> 2;        // 0..1 (N)
    const int r16  = lane & 15;
    const int quad = lane >> 4;

    // XCD-chunked block swizzle (nwg=512 % 8 == 0 -> bijective).
    const int nwg = gridDim.x;
    int swz = blockIdx.x;
    if ((nwg & 7) == 0) swz = (swz & 7) * (nwg >> 3) + (swz >> 3);
    const int bm = (swz >> 3) * 256;           // 64 m-panels
    const int bn = (swz & 7) * 128;            // 8 n-panels share one x panel (L2/L3)

    // ---- A staging: thread t owns chunks t (rows 0..63) and t+512 (rows 64..127)
    //      of each [128][32]f32 half. Chunk g: row g>>3, pos g&7, src chunk
    //      (g&7)^(row&7). Note (t+512)>>3 = 64+(t>>3) and &7 unchanged -> same ac.
    const int ar = t >> 3;                     // 0..63
    const int ac = (t & 7) ^ (ar & 7);         // pre-swizzled src chunk pos
    const float* gA = Xf + (size_t)(bm + ar) * 1024 + ac * 4;
    const int adst = t * 16;                   // byte dest (chunk t); +8192 = chunk t+512

    // ---- B staging (R7 pattern, verified) ----
    const int brw = t >> 2;
    const int bcc = (t & 3) ^ ((brw >> 1) & 3);
    const unsigned short* pB = Wt + (size_t)(bn + brw) * 1024 + bcc * 8;
    const int bdst = 32768 + t * 16;           // byte dest in B region

    // ---- reader constants ----
    const int o0  = ((2 * quad) ^ (r16 & 7)) * 16;       // A chunk lo (bytes)
    const int o1  = ((2 * quad + 1) ^ (r16 & 7)) * 16;   // A chunk hi
    const int hA0 = (wr * 16 + r16) * 128;               // frag mt&1==0 row base
    const int hA1 = ((4 + wr) * 16 + r16) * 128;         // frag mt&1==1
    const int bB0 = 32768 + (wc * 16 + r16) * 64 + (quad ^ ((r16 >> 1) & 3)) * 16;
    // fb[nt] at bB0 + nt*2048 (rows (wc+2*nt)*16 + r16)

    f32x4 acc[4][4];
#pragma unroll
    for (int i = 0; i < 4; ++i)
#pragma unroll
        for (int jj = 0; jj < 4; ++jj)
            acc[i][jj] = (f32x4){0.f, 0.f, 0.f, 0.f};

#define STAGE_A(HALF, BUF, K)                                                     \
    do { gld16(gA + (HALF) * 131072 + (K),         lds + (BUF) + (HALF) * 16384 + adst);        \
         gld16(gA + (HALF) * 131072 + 65536 + (K), lds + (BUF) + (HALF) * 16384 + 8192 + adst); \
         FENCE(); } while (0)
#define STAGE_B(BUF, K)                                                           \
    do { gld16(pB + (K), lds + (BUF) + bdst); FENCE(); } while (0)

    // ---- prologue: tile0 (A0,B,A1) -> buf0; tile1 (A0,B) -> buf1 ----
    STAGE_A(0, 0, 0);            // 2
    STAGE_B(0, 0);               // 1
    STAGE_A(1, 0, 0);            // 2
    STAGE_A(0, 40960, 32);       // 2
    STAGE_B(40960, 32);          // 1  -> 8 outstanding
    asm volatile("s_waitcnt vmcnt(3)" ::: "memory");   // tile0 (first 5) landed
    BARRIER();

#pragma unroll 2
    for (int j = 0; j < 32; ++j) {
        const int cur = (j & 1) * 40960;
        const int nxt = cur ^ 40960;

        // ---------- phase 0: A-half0 + all fb; stage A1(j+1) -> nxt ----------
        f32x4 a0l = *(const f32x4*)(lds + cur + hA0 + o0);
        f32x4 a0h = *(const f32x4*)(lds + cur + hA0 + o1);
        f32x4 a1l = *(const f32x4*)(lds + cur + hA1 + o0);
        f32x4 a1h = *(const f32x4*)(lds + cur + hA1 + o1);
        bf16x8 fb[4];
#pragma unroll
        for (int nt = 0; nt < 4; ++nt)
            fb[nt] = *(const bf16x8*)(lds + cur + bB0 + nt * 2048);
        if (j < 31) STAGE_A(1, nxt, (j + 1) * 32);
        BARRIER();
        asm volatile("s_waitcnt lgkmcnt(0)" ::: "memory");
        __builtin_amdgcn_sched_barrier(0);                 // rule 18
        __builtin_amdgcn_s_setprio(1);
        {
            bf16x8 fa0 = cvt8(a0l, a0h), fa1 = cvt8(a1l, a1h);
#pragma unroll
            for (int nt = 0; nt < 4; ++nt) {
                acc[0][nt] = __builtin_amdgcn_mfma_f32_16x16x32_bf16(fa0, fb[nt], acc[0][nt], 0, 0, 0);
                acc[1][nt] = __builtin_amdgcn_mfma_f32_16x16x32_bf16(fa1, fb[nt], acc[1][nt], 0, 0, 0);
            }
        }
        __builtin_amdgcn_s_setprio(0);
        BARRIER();

        // ---------- phase 1: A-half1; stage A0,B(j+2) -> cur; checkpoint ----------
        f32x4 a2l = *(const f32x4*)(lds + cur + 16384 + hA0 + o0);
        f32x4 a2h = *(const f32x4*)(lds + cur + 16384 + hA0 + o1);
        f32x4 a3l = *(const f32x4*)(lds + cur + 16384 + hA1 + o0);
        f32x4 a3h = *(const f32x4*)(lds + cur + 16384 + hA1 + o1);
        if (j < 30) { STAGE_A(0, cur, (j + 2) * 32); STAGE_B(cur, (j + 2) * 32); }
        if (j < 30)       asm volatile("s_waitcnt vmcnt(3)" ::: "memory");
        else if (j == 30) asm volatile("s_waitcnt vmcnt(0)" ::: "memory");
        BARRIER();
        asm volatile("s_waitcnt lgkmcnt(0)" ::: "memory");
        __builtin_amdgcn_sched_barrier(0);
        __builtin_amdgcn_s_setprio(1);
        {
            bf16x8 fa2 = cvt8(a2l, a2h), fa3 = cvt8(a3l, a3h);
#pragma unroll
            for (int nt = 0; nt < 4; ++nt) {
                acc[2][nt] = __builtin_amdgcn_mfma_f32_16x16x32_bf16(fa2, fb[nt], acc[2][nt], 0, 0, 0);
                acc[3][nt] = __builtin_amdgcn_mfma_f32_16x16x32_bf16(fa3, fb[nt], acc[3][nt], 0, 0, 0);
            }
        }
        __builtin_amdgcn_s_setprio(0);
        BARRIER();
    }
#undef STAGE_A
#undef STAGE_B

    // ---- epilogue: frag (mt,nt) -> rows bm+(4mt+wr)*16+quad*4, cols bn+(wc+2nt)*16+r16 ----
    const int orow0 = bm + wr * 16 + quad * 4;
    const int ocol0 = bn + wc * 16 + r16;
#pragma unroll
    for (int nt = 0; nt < 4; ++nt) {
        const float bv = bias[ocol0 + nt * 32];
#pragma unroll
        for (int mt = 0; mt < 4; ++mt) {
            float* orow = out + (size_t)(orow0 + mt * 64) * 1024 + (ocol0 + nt * 32);
#pragma unroll
            for (int i = 0; i < 4; ++i)
                orow[(size_t)i * 1024] = acc[mt][nt][i] + bv;
        }
    }
}

// ---------------- fallback gemm (ws too small): old 128x128, fp32 A ----------------
template <bool XF32>
__global__ __launch_bounds__(256) void gemm_bt(
    const void* __restrict__ X_, const unsigned short* __restrict__ Wt,
    const float* __restrict__ bias, float* __restrict__ out)
{
    __shared__ __align__(16) unsigned short lA[128 * 32];
    __shared__ __align__(16) unsigned short lB[128 * 32];

    const int t    = threadIdx.x;
    const int lane = t & 63;
    const int w    = t >> 6;
    const int bm   = blockIdx.x * 128;
    const int bn   = blockIdx.y * 128;
    const int wm   = (w & 1) * 64;
    const int wn   = (w >> 1) * 64;
    const int r16  = lane & 15;
    const int quad = lane >> 4;

    const int srow = t >> 2;
    const int gc   = (t & 3) ^ ((srow >> 1) & 3);
    unsigned short* lsA = lA + t * 8;
    unsigned short* lsB = lB + t * 8;
    const size_t ga0 = (size_t)(bm + srow) * 1024 + gc * 8;
    const size_t ga1 = (size_t)(bm + srow + 64) * 1024 + gc * 8;
    const unsigned short* gB0 = Wt + (size_t)(bn + srow) * 1024 + gc * 8;

    const int p    = (quad ^ ((r16 >> 1) & 3)) * 8;
    const int aoff = (wm + r16) * 32 + p;
    const int boff = (wn + r16) * 32 + p;

    const unsigned short* Xb = (const unsigned short*)X_;
    const float*          Xf = (const float*)X_;

    f32x4 acc[4][4];
#pragma unroll
    for (int i = 0; i < 4; ++i)
#pragma unroll
        for (int j = 0; j < 4; ++j) {
            f32x4 z = {0.f, 0.f, 0.f, 0.f};
            acc[i][j] = z;
        }

    for (int kt = 0; kt < 1024; kt += 32) {
        if (XF32) {
            f32x4 a0 = *(const f32x4*)(Xf + ga0 + kt);
            f32x4 a1 = *(const f32x4*)(Xf + ga0 + kt + 4);
            f32x4 a2 = *(const f32x4*)(Xf + ga1 + kt);
            f32x4 a3 = *(const f32x4*)(Xf + ga1 + kt + 4);
            *(ushort8*)lsA          = cvt8u(a0, a1);
            *(ushort8*)(lsA + 2048) = cvt8u(a2, a3);
        } else {
            gld16(Xb + ga0 + kt, lsA);
            gld16(Xb + ga1 + kt, lsA + 2048);
        }
        gld16(gB0 + kt,             lsB);
        gld16(gB0 + kt + 64 * 1024, lsB + 2048);
        __syncthreads();

        bf16x8 fa[4], fb[4];
#pragma unroll
        for (int mt = 0; mt < 4; ++mt) fa[mt] = *(const bf16x8*)(lA + aoff + mt * 16 * 32);
#pragma unroll
        for (int nt = 0; nt < 4; ++nt) fb[nt] = *(const bf16x8*)(lB + boff + nt * 16 * 32);

#pragma unroll
        for (int mt = 0; mt < 4; ++mt)
#pragma unroll
            for (int nt = 0; nt < 4; ++nt)
                acc[mt][nt] = __builtin_amdgcn_mfma_f32_16x16x32_bf16(
                    fa[mt], fb[nt], acc[mt][nt], 0, 0, 0);

        __syncthreads();
    }

    const int orow0 = bm + wm + quad * 4;
    const int ocol0 = bn + wn + r16;
#pragma unroll
    for (int nt = 0; nt < 4; ++nt) {
        const float bv = bias[ocol0 + nt * 16];
#pragma unroll
        for (int mt = 0; mt < 4; ++mt)
#pragma unroll
            for (int i = 0; i < 4; ++i)
                out[(size_t)(orow0 + mt * 16 + i) * 1024 + (ocol0 + nt * 16)] =
                    acc[mt][nt][i] + bv;
    }
}

extern "C" void kernel_launch(void* const* d_in, const int* in_sizes, int n_in,
                              void* d_out, int out_size, void* d_ws, size_t ws_size,
                              hipStream_t stream) {
    const float* x  = (const float*)d_in[0];   // [M][1024]
    const float* W  = (const float*)d_in[1];   // [1024][1024]
    const float* b  = (const float*)d_in[2];   // [1024]
    const float* A  = (const float*)d_in[3];   // [16][1024]
    const float* Bm = (const float*)d_in[4];   // [1024][16]
    float* out = (float*)d_out;

    const int M = in_sizes[0] / 1024;          // 16384

    const bool fast = (ws_size >= (2u << 20) + 4096) && (M % 256 == 0);
    unsigned short* Weff = (unsigned short*)d_ws;
    hipLaunchKernelGGL(prep, dim3(512), dim3(256), 0, stream, W, A, Bm, Weff);
    if (fast) {
        hipLaunchKernelGGL(gemm256, dim3((M / 256) * 8), dim3(512), 81920, stream,
                           x, Weff, b, out);
    } else {
        hipLaunchKernelGGL((gemm_bt<true>), dim3(M / 128, 8), dim3(256), 0, stream,
                           (const void*)x, Weff, b, out);
    }
}

// Round 9
// 168.828 us; speedup vs baseline: 1.0594x; 1.0594x over previous
//
#include <hip/hip_runtime.h>

// LoRA linear, fp32 in/out: out = x @ (W + 2*B@A)^T + b
//   prep:   Weff = bf16(W + 2*B@A) only (2 MiB, 512 blocks, ~5us). No xbf pass —
//           gemm stages x fp32 directly into LDS via global_load_lds and converts
//           to bf16 after lgkmcnt(0) (R8 mechanism, correctness-verified).
//   gemm256: R9: tile TRANSPOSED vs R8 to fix the occupancy kill: BM=128, BN=256,
//           BK=32 -> buf = A f32 16KB + B bf16 16KB = 32KB, dbuf 64KB/block ->
//           2 blocks/CU with 32KB slack (R8's 80KB needed exactly 160KB -> 1/CU, 2x).
//           8 waves 4Mx2N, acc[2][8]. p0: read A(cvt in-phase)+fb[0..3], stage
//           B1(j+1)->nxt; p1: read fb[4..7], stage A(j+2)+B0(j+2)->cur, vmcnt(3).
//           Swizzles HW-verified: A c^(r&7) (R8 reader), B c^((r>>1)&3) (R7, 0 cf).
//   Fallback (ws too small): old 128x128 kernel, A staged via fp32 loads + HW cvt.

typedef __bf16 bf16x8 __attribute__((ext_vector_type(8)));
typedef float f32x4 __attribute__((ext_vector_type(4)));
typedef unsigned short ushort8 __attribute__((ext_vector_type(8)));

__device__ __forceinline__ unsigned short f2bf(float f) {
    __bf16 h = (__bf16)f;                       // HW RNE convert
    union { __bf16 b; unsigned short u; } v; v.b = h; return v.u;
}
__device__ __forceinline__ ushort8 cvt8u(f32x4 a, f32x4 b) {
    ushort8 o;
#pragma unroll
    for (int i = 0; i < 4; ++i) { o[i] = f2bf(a[i]); o[i + 4] = f2bf(b[i]); }
    return o;
}
__device__ __forceinline__ bf16x8 cvt8(f32x4 a, f32x4 b) {
    union { ushort8 u; bf16x8 h; } v; v.u = cvt8u(a, b); return v.h;
}
__device__ __forceinline__ void gld16(const void* g, void* l) {
    __builtin_amdgcn_global_load_lds(
        (const __attribute__((address_space(1))) unsigned int*)g,
        (__attribute__((address_space(3))) unsigned int*)l, 16, 0, 0);
}

#define FENCE() asm volatile("" ::: "memory")
#define BARRIER() do { FENCE(); __builtin_amdgcn_s_barrier(); FENCE(); } while (0)

// ---------------- prep: Weff fold only (512 blocks) ----------------
__global__ __launch_bounds__(256) void prep(
    const float* __restrict__ W, const float* __restrict__ A,
    const float* __restrict__ B, unsigned short* __restrict__ Weff)
{
    const int idx = blockIdx.x * 256 + threadIdx.x;
    const int o  = idx >> 7;
    const int kc = (idx & 127) << 3;
    float br[16];
#pragma unroll
    for (int r = 0; r < 16; ++r) br[r] = 2.0f * B[o * 16 + r];
    float acc[8];
    const float* wrow = W + (size_t)o * 1024 + kc;
#pragma unroll
    for (int j = 0; j < 8; ++j) acc[j] = wrow[j];
#pragma unroll
    for (int r = 0; r < 16; ++r) {
        const float* arow = A + r * 1024 + kc;
#pragma unroll
        for (int j = 0; j < 8; ++j) acc[j] += br[r] * arow[j];
    }
    ushort8 o8;
#pragma unroll
    for (int j = 0; j < 8; ++j) o8[j] = f2bf(acc[j]);
    *(ushort8*)(Weff + (size_t)o * 1024 + kc) = o8;
}

// ---------------- gemm256: 128x256x32, fp32-A-in-LDS, 2 blocks/CU ----------------
// Geometry: BM=128, BN=256, BK=32, 512 thr = 8 waves (4M x 2N: wr=w&3, wc=w>>2).
//   Per-wave out 32x128: m-frags rows (wr*2+mt)*16 (mt=0..1), n-frags cols
//   (wc+2*nt)*16 (nt=0..7; nt<4 in B-half0, nt>=4 in B-half1).
// LDS 64 KiB: 2 bufs (stride 32768 B) x {A f32 [128][32] @0 (16384), B0 bf16
//   [128 nrows][32] @16384 (8192), B1 @24576 (8192)}.
// Swizzle A (128B rows, 8 chunks): pos p holds src chunk p^(r&7); reader lane
//   (r16,q) reads pos (2q)^(r16&7),(2q+1)^(r16&7): 8 lanes/bank-group -> free.
// Swizzle B: c^((r>>1)&3) on 64B rows (R7: measured 0 conflicts).
// Pipeline (tile j): p0: ds_read A (4xb128) + fb[0..3]; stage B1(j+1)->nxt;
//   barrier; lgkmcnt(0); cvt A->fa0,fa1 (regs, live both phases); MFMA x fb[0..3].
//   p1: ds_read fb[4..7]; stage A(j+2)x2,B0(j+2)->cur; checkpoint; MFMA x fb[4..7].
// vmcnt ledger (4 loads/tile: B1 @p0; A x2, B0 @p1): at tile j p1 outstanding =
//   [A(j+1)x2,B0(j+1)](j-1 p1) + [B1(j+1)](j p0) + [A(j+2)x2,B0(j+2)](j p1) = 7
//   -> vmcnt(3) retires oldest 4 = all of tile j+1. Peel: stages stop at j>=30
//   (A/B0) and j>=31 (B1); j==30 -> vmcnt(0) drains tile31's 4; j==31 none.
__global__ __launch_bounds__(512, 4) void gemm256(
    const float* __restrict__ Xf,              // fp32 x [M][1024]
    const unsigned short* __restrict__ Wt,     // bf16 Weff [1024][1024]
    const float* __restrict__ bias,            // fp32 [1024]
    float* __restrict__ out)                   // fp32 [M][1024]
{
    extern __shared__ __align__(16) char lds[];   // 65536 B

    const int t    = threadIdx.x;
    const int lane = t & 63;
    const int w    = t >> 6;
    const int wr   = w & 3;         // 0..3 (M)
    const int wc   = w >> 2;        // 0..1 (N)
    const int r16  = lane & 15;
    const int quad = lane >> 4;

    // XCD-chunked block swizzle (nwg=512 % 8 == 0 -> bijective).
    const int nwg = gridDim.x;
    int swz = blockIdx.x;
    if ((nwg & 7) == 0) swz = (swz & 7) * (nwg >> 3) + (swz >> 3);
    const int bm = (swz >> 2) * 128;           // 128 m-panels
    const int bn = (swz & 3) * 256;            // 4 n-panels share one x panel (L2/L3)

    // ---- A staging: thread t owns chunks t (rows 0..63) and t+512 (rows 64..127).
    //      Chunk g: row g>>3, pos g&7, src chunk (g&7)^(row&7); (row+64)&7 == row&7.
    const int ar = t >> 3;                     // 0..63
    const int ac = (t & 7) ^ (ar & 7);         // pre-swizzled src chunk pos
    const float* gA = Xf + (size_t)(bm + ar) * 1024 + ac * 4;
    const int adst = t * 16;                   // byte dest (chunk t); +8192 = row+64

    // ---- B staging (R7 pattern, verified): per half, thread t owns chunk t ----
    const int brw = t >> 2;                    // half-local n-row 0..127
    const int bcc = (t & 3) ^ ((brw >> 1) & 3);
    const unsigned short* pB0 = Wt + (size_t)(bn + brw) * 1024 + bcc * 8;
    const unsigned short* pB1 = pB0 + 131072;  // +128 n-rows
    const int bdst = t * 16;                   // byte dest within half region

    // ---- reader constants ----
    const int o0 = ((2 * quad) ^ (r16 & 7)) * 16;        // A chunk lo (bytes)
    const int o1 = ((2 * quad + 1) ^ (r16 & 7)) * 16;    // A chunk hi
    const int hA0 = ((wr * 2 + 0) * 16 + r16) * 128;     // frag mt=0 row byte base
    const int hA1 = ((wr * 2 + 1) * 16 + r16) * 128;     // frag mt=1
    const int bB0 = 16384 + (wc * 16 + r16) * 64 + (quad ^ ((r16 >> 1) & 3)) * 16;
    // fb[nt]: nt<4 -> bB0 + nt*2048 ; nt>=4 -> bB0 + 8192 + (nt-4)*2048

    f32x4 acc[2][8];
#pragma unroll
    for (int i = 0; i < 2; ++i)
#pragma unroll
        for (int jj = 0; jj < 8; ++jj)
            acc[i][jj] = (f32x4){0.f, 0.f, 0.f, 0.f};

#define STAGE_A(BUF, K)                                                        \
    do { gld16(gA + (K),             lds + (BUF) + adst);                      \
         gld16(gA + 65536 + (K),     lds + (BUF) + 8192 + adst);               \
         FENCE(); } while (0)
#define STAGE_B0(BUF, K) do { gld16(pB0 + (K), lds + (BUF) + 16384 + bdst); FENCE(); } while (0)
#define STAGE_B1(BUF, K) do { gld16(pB1 + (K), lds + (BUF) + 24576 + bdst); FENCE(); } while (0)

    // ---- prologue: tile0 (A,B0,B1) -> buf0; tile1 (A,B0) -> buf1 ----
    STAGE_A(0, 0);               // 2
    STAGE_B0(0, 0);              // 1
    STAGE_B1(0, 0);              // 1   (tile0 complete: 4)
    STAGE_A(32768, 32);          // 2
    STAGE_B0(32768, 32);         // 1   -> 7 outstanding
    asm volatile("s_waitcnt vmcnt(3)" ::: "memory");   // tile0 fully landed
    BARRIER();

#pragma unroll 2
    for (int j = 0; j < 32; ++j) {
        const int cur = (j & 1) * 32768;
        const int nxt = cur ^ 32768;

        // ---------- phase 0: read A + fb[0..3]; stage B1(j+1) -> nxt ----------
        f32x4 a0l = *(const f32x4*)(lds + cur + hA0 + o0);
        f32x4 a0h = *(const f32x4*)(lds + cur + hA0 + o1);
        f32x4 a1l = *(const f32x4*)(lds + cur + hA1 + o0);
        f32x4 a1h = *(const f32x4*)(lds + cur + hA1 + o1);
        bf16x8 fb[4];
#pragma unroll
        for (int nt = 0; nt < 4; ++nt)
            fb[nt] = *(const bf16x8*)(lds + cur + bB0 + nt * 2048);
        if (j < 31) STAGE_B1(nxt, (j + 1) * 32);
        BARRIER();
        asm volatile("s_waitcnt lgkmcnt(0)" ::: "memory");
        __builtin_amdgcn_sched_barrier(0);                 // rule 18
        __builtin_amdgcn_s_setprio(1);
        bf16x8 fa0 = cvt8(a0l, a0h), fa1 = cvt8(a1l, a1h); // live across phases
#pragma unroll
        for (int nt = 0; nt < 4; ++nt) {
            acc[0][nt] = __builtin_amdgcn_mfma_f32_16x16x32_bf16(fa0, fb[nt], acc[0][nt], 0, 0, 0);
            acc[1][nt] = __builtin_amdgcn_mfma_f32_16x16x32_bf16(fa1, fb[nt], acc[1][nt], 0, 0, 0);
        }
        __builtin_amdgcn_s_setprio(0);
        BARRIER();

        // ---------- phase 1: read fb[4..7]; stage A,B0(j+2) -> cur; checkpoint ----------
#pragma unroll
        for (int nt = 0; nt < 4; ++nt)
            fb[nt] = *(const bf16x8*)(lds + cur + bB0 + 8192 + nt * 2048);
        if (j < 30) { STAGE_A(cur, (j + 2) * 32); STAGE_B0(cur, (j + 2) * 32); }
        if (j < 30)       asm volatile("s_waitcnt vmcnt(3)" ::: "memory");
        else if (j == 30) asm volatile("s_waitcnt vmcnt(0)" ::: "memory");
        BARRIER();
        asm volatile("s_waitcnt lgkmcnt(0)" ::: "memory");
        __builtin_amdgcn_sched_barrier(0);
        __builtin_amdgcn_s_setprio(1);
#pragma unroll
        for (int nt = 0; nt < 4; ++nt) {
            acc[0][nt + 4] = __builtin_amdgcn_mfma_f32_16x16x32_bf16(fa0, fb[nt], acc[0][nt + 4], 0, 0, 0);
            acc[1][nt + 4] = __builtin_amdgcn_mfma_f32_16x16x32_bf16(fa1, fb[nt], acc[1][nt + 4], 0, 0, 0);
        }
        __builtin_amdgcn_s_setprio(0);
        BARRIER();
    }
#undef STAGE_A
#undef STAGE_B0
#undef STAGE_B1

    // ---- epilogue: frag (mt,nt) -> rows bm+(wr*2+mt)*16+quad*4, cols bn+(wc+2nt)*16+r16 ----
    const int orow0 = bm + wr * 32 + quad * 4;
    const int ocol0 = bn + wc * 16 + r16;
#pragma unroll
    for (int nt = 0; nt < 8; ++nt) {
        const float bv = bias[ocol0 + nt * 32];
#pragma unroll
        for (int mt = 0; mt < 2; ++mt) {
            float* orow = out + (size_t)(orow0 + mt * 16) * 1024 + (ocol0 + nt * 32);
#pragma unroll
            for (int i = 0; i < 4; ++i)
                orow[(size_t)i * 1024] = acc[mt][nt][i] + bv;
        }
    }
}

// ---------------- fallback gemm (ws too small): old 128x128, fp32 A ----------------
template <bool XF32>
__global__ __launch_bounds__(256) void gemm_bt(
    const void* __restrict__ X_, const unsigned short* __restrict__ Wt,
    const float* __restrict__ bias, float* __restrict__ out)
{
    __shared__ __align__(16) unsigned short lA[128 * 32];
    __shared__ __align__(16) unsigned short lB[128 * 32];

    const int t    = threadIdx.x;
    const int lane = t & 63;
    const int w    = t >> 6;
    const int bm   = blockIdx.x * 128;
    const int bn   = blockIdx.y * 128;
    const int wm   = (w & 1) * 64;
    const int wn   = (w >> 1) * 64;
    const int r16  = lane & 15;
    const int quad = lane >> 4;

    const int srow = t >> 2;
    const int gc   = (t & 3) ^ ((srow >> 1) & 3);
    unsigned short* lsA = lA + t * 8;
    unsigned short* lsB = lB + t * 8;
    const size_t ga0 = (size_t)(bm + srow) * 1024 + gc * 8;
    const size_t ga1 = (size_t)(bm + srow + 64) * 1024 + gc * 8;
    const unsigned short* gB0 = Wt + (size_t)(bn + srow) * 1024 + gc * 8;

    const int p    = (quad ^ ((r16 >> 1) & 3)) * 8;
    const int aoff = (wm + r16) * 32 + p;
    const int boff = (wn + r16) * 32 + p;

    const unsigned short* Xb = (const unsigned short*)X_;
    const float*          Xf = (const float*)X_;

    f32x4 acc[4][4];
#pragma unroll
    for (int i = 0; i < 4; ++i)
#pragma unroll
        for (int j = 0; j < 4; ++j) {
            f32x4 z = {0.f, 0.f, 0.f, 0.f};
            acc[i][j] = z;
        }

    for (int kt = 0; kt < 1024; kt += 32) {
        if (XF32) {
            f32x4 a0 = *(const f32x4*)(Xf + ga0 + kt);
            f32x4 a1 = *(const f32x4*)(Xf + ga0 + kt + 4);
            f32x4 a2 = *(const f32x4*)(Xf + ga1 + kt);
            f32x4 a3 = *(const f32x4*)(Xf + ga1 + kt + 4);
            *(ushort8*)lsA          = cvt8u(a0, a1);
            *(ushort8*)(lsA + 2048) = cvt8u(a2, a3);
        } else {
            gld16(Xb + ga0 + kt, lsA);
            gld16(Xb + ga1 + kt, lsA + 2048);
        }
        gld16(gB0 + kt,             lsB);
        gld16(gB0 + kt + 64 * 1024, lsB + 2048);
        __syncthreads();

        bf16x8 fa[4], fb[4];
#pragma unroll
        for (int mt = 0; mt < 4; ++mt) fa[mt] = *(const bf16x8*)(lA + aoff + mt * 16 * 32);
#pragma unroll
        for (int nt = 0; nt < 4; ++nt) fb[nt] = *(const bf16x8*)(lB + boff + nt * 16 * 32);

#pragma unroll
        for (int mt = 0; mt < 4; ++mt)
#pragma unroll
            for (int nt = 0; nt < 4; ++nt)
                acc[mt][nt] = __builtin_amdgcn_mfma_f32_16x16x32_bf16(
                    fa[mt], fb[nt], acc[mt][nt], 0, 0, 0);

        __syncthreads();
    }

    const int orow0 = bm + wm + quad * 4;
    const int ocol0 = bn + wn + r16;
#pragma unroll
    for (int nt = 0; nt < 4; ++nt) {
        const float bv = bias[ocol0 + nt * 16];
#pragma unroll
        for (int mt = 0; mt < 4; ++mt)
#pragma unroll
            for (int i = 0; i < 4; ++i)
                out[(size_t)(orow0 + mt * 16 + i) * 1024 + (ocol0 + nt * 16)] =
                    acc[mt][nt][i] + bv;
    }
}

extern "C" void kernel_launch(void* const* d_in, const int* in_sizes, int n_in,
                              void* d_out, int out_size, void* d_ws, size_t ws_size,
                              hipStream_t stream) {
    const float* x  = (const float*)d_in[0];   // [M][1024]
    const float* W  = (const float*)d_in[1];   // [1024][1024]
    const float* b  = (const float*)d_in[2];   // [1024]
    const float* A  = (const float*)d_in[3];   // [16][1024]
    const float* Bm = (const float*)d_in[4];   // [1024][16]
    float* out = (float*)d_out;

    const int M = in_sizes[0] / 1024;          // 16384

    const bool fast = (ws_size >= (2u << 20) + 4096) && (M % 128 == 0);
    unsigned short* Weff = (unsigned short*)d_ws;
    hipLaunchKernelGGL(prep, dim3(512), dim3(256), 0, stream, W, A, Bm, Weff);
    if (fast) {
        hipLaunchKernelGGL(gemm256, dim3((M / 128) * 4), dim3(512), 65536, stream,
                           x, Weff, b, out);
    } else {
        hipLaunchKernelGGL((gemm_bt<true>), dim3(M / 128, 8), dim3(256), 0, stream,
                           (const void*)x, Weff, b, out);
    }
}

// Round 11
// 155.130 us; speedup vs baseline: 1.1529x; 1.0883x over previous
//
#include <hip/hip_runtime.h>

// LoRA linear, fp32 in/out: out = x @ (W + 2*B@A)^T + b
//   prep:   [0..511] Weff = bf16(W + 2*B@A) (2 MiB); [512..] xbf = bf16(x) (32 MiB).
//           fp32-x-direct in gemm is DEAD (R4/R6/R8/R9: 75-128us vs 42-46us bf16).
//   gemm256: R10 = R2 x R7 hybrid: BM=128, BN=128, BK=64, 2-phase, 2 blocks/CU.
//           vs R7 (256x128x32): same phase length (8 MFMA), but per-64K: LDS reads
//           12 vs 20 b128, staged 32 vs 48 KB, checkpoints/barriers HALVED (16
//           tiles not 32). acc[2][4]=32 VGPR -> occupancy-2 safe. All-bf16.
//           Swizzle (128B rows): chunk c of row r at pos c^(r&7) (R8-verified
//           reader, 2-way/free). Ledger = R9's verified shape: 4 gld16/tile
//           (B1 | Aa,Ab,B0), vmcnt(3) at p1 retires exactly tile j+1.
//           (R11 = R10 resubmit: R10 bench was a container/infra failure, same
//           signature as R5->R6; schedule re-audited — barriers uniform, ledger
//           exact, LDS write-after-read safe, swizzle algebra verified.)
//   Fallback (ws too small): old 128x128 kernel, A staged via fp32 loads + HW cvt.

typedef __bf16 bf16x8 __attribute__((ext_vector_type(8)));
typedef float f32x4 __attribute__((ext_vector_type(4)));
typedef unsigned short ushort8 __attribute__((ext_vector_type(8)));

__device__ __forceinline__ unsigned short f2bf(float f) {
    __bf16 h = (__bf16)f;                       // HW RNE convert
    union { __bf16 b; unsigned short u; } v; v.b = h; return v.u;
}
__device__ __forceinline__ ushort8 cvt8u(f32x4 a, f32x4 b) {
    ushort8 o;
#pragma unroll
    for (int i = 0; i < 4; ++i) { o[i] = f2bf(a[i]); o[i + 4] = f2bf(b[i]); }
    return o;
}
__device__ __forceinline__ void gld16(const void* g, void* l) {
    __builtin_amdgcn_global_load_lds(
        (const __attribute__((address_space(1))) unsigned int*)g,
        (__attribute__((address_space(3))) unsigned int*)l, 16, 0, 0);
}

#define FENCE() asm volatile("" ::: "memory")
#define BARRIER() do { FENCE(); __builtin_amdgcn_s_barrier(); FENCE(); } while (0)

// ---------------- prep: Weff fold + x conversion ----------------
__global__ __launch_bounds__(256) void prep(
    const float* __restrict__ X, const float* __restrict__ W,
    const float* __restrict__ A, const float* __restrict__ B,
    unsigned short* __restrict__ xbf, unsigned short* __restrict__ Weff)
{
    const int b = blockIdx.x;
    if (b < 512) {
        const int idx = b * 256 + threadIdx.x;
        const int o  = idx >> 7;
        const int kc = (idx & 127) << 3;
        float br[16];
#pragma unroll
        for (int r = 0; r < 16; ++r) br[r] = 2.0f * B[o * 16 + r];
        float acc[8];
        const float* wrow = W + (size_t)o * 1024 + kc;
#pragma unroll
        for (int j = 0; j < 8; ++j) acc[j] = wrow[j];
#pragma unroll
        for (int r = 0; r < 16; ++r) {
            const float* arow = A + r * 1024 + kc;
#pragma unroll
            for (int j = 0; j < 8; ++j) acc[j] += br[r] * arow[j];
        }
        ushort8 o8;
#pragma unroll
        for (int j = 0; j < 8; ++j) o8[j] = f2bf(acc[j]);
        *(ushort8*)(Weff + (size_t)o * 1024 + kc) = o8;
    } else {
        const size_t i = ((size_t)(b - 512) * 256 + threadIdx.x) * 8;
        f32x4 a = *(const f32x4*)(X + i);
        f32x4 c = *(const f32x4*)(X + i + 4);
        *(ushort8*)(xbf + i) = cvt8u(a, c);
    }
}

// ---------------- gemm256: 128x128x64, 2 phases/tile, 2 blocks/CU ----------------
// Geometry: BM=BN=128, BK=64, 512 thr = 8 waves (4M x 2N: wr=w&3, wc=w>>2).
//   Per-wave out 32x64: m-frags rows (4*mt+wr)*16 (mt=0..1; mt=0 -> A rows 0..63,
//   mt=1 -> rows 64..127), n-frags cols (2*nt+wc)*16 (nt=0..3; nt<2 -> B rows
//   0..63, nt>=2 -> 64..127).
// LDS 64 KiB: 2 bufs (stride 32768 B) x {A bf16 [128][64] @0 (16384 B),
//   B bf16 [128][64] @16384}. Halves: Aa rows 0-63 @0, Ab @8192; B0 @16384,
//   B1 @24576. Each half = 8 KB = 1 gld16 call (512 thr x 16 B).
// Swizzle (128 B rows = 8 x 16B chunks): pos p of row r holds src chunk p^(r&7).
//   Reader lane (r16,q), ks: pos (ks*4+q)^(r16&7) -> 16-lane phase covers all 8
//   positions 2x -> 2-way, free (R8 reader, HW-verified). Source pre-swizzled,
//   LDS dest linear (rule #21).
// Pipeline (tile j = k 64j..64j+63):
//   p0: ds_read fa[0..1][0..1] (4 b128) + fb[0..1][0..1] (4); stage B1(j+1)->nxt;
//       barrier; lgkmcnt(0); MFMA (m x n01, 8); barrier.
//   p1: ds_read fb[2..3][0..1] (4); stage Aa,Ab,B0(j+2)->cur (A/B0 cur last read
//       at p0, drained before p0's trailing barrier); checkpoint; MFMA (m x n23).
// vmcnt ledger (4 loads/tile, order B1 | Aa,Ab,B0): at tile j p1 outstanding =
//   [Aa,Ab,B0](j+1)[j-1 p1] + [B1(j+1)][j p0] + [Aa,Ab,B0](j+2)[j p1] = 7
//   -> vmcnt(3) retires oldest 4 = all of tile j+1. Peel: B1 stops j>=15,
//   Aa/Ab/B0 stop j>=14; j==14 -> vmcnt(0) (tile15's 4); j==15 none.
__global__ __launch_bounds__(512, 4) void gemm256(
    const unsigned short* __restrict__ Xb,     // bf16 x [M][1024]
    const unsigned short* __restrict__ Wt,     // bf16 Weff [1024][1024]
    const float* __restrict__ bias,            // fp32 [1024]
    float* __restrict__ out)                   // fp32 [M][1024]
{
    extern __shared__ __align__(16) char lds[];   // 65536 B

    const int t    = threadIdx.x;
    const int lane = t & 63;
    const int w    = t >> 6;
    const int wr   = w & 3;         // 0..3 (M)
    const int wc   = w >> 2;        // 0..1 (N)
    const int r16  = lane & 15;
    const int quad = lane >> 4;

    // XCD-chunked block swizzle (nwg=1024 % 8 == 0 -> bijective).
    const int nwg = gridDim.x;
    int swz = blockIdx.x;
    if ((nwg & 7) == 0) swz = (swz & 7) * (nwg >> 3) + (swz >> 3);
    const int bm = (swz >> 3) * 128;           // 128 m-panels
    const int bn = (swz & 7) * 128;            // 8 n-panels share one x panel (L2)

    // ---- staging: thread t owns 16B chunk t of each 8 KB half (rows 0..63) ----
    // chunk t: row t>>3, pos t&7, src chunk (t&7)^(row&7).
    const int ar = t >> 3;                     // 0..63
    const int ac = (t & 7) ^ (ar & 7);         // pre-swizzled src chunk
    const unsigned short* gA = Xb + (size_t)(bm + ar) * 1024 + ac * 8;
    const unsigned short* gB = Wt + (size_t)(bn + ar) * 1024 + ac * 8;
    const int adst = t * 16;                   // byte dest within half region

    // ---- reader constants ----
    const int sw0 = ((quad) ^ (r16 & 7)) * 16;       // ks=0 chunk byte offset
    const int sw1 = sw0 ^ 64;                        // ks=1 ((4+quad)^h = pos0^4)
    const int aB  = wr * 2048 + r16 * 128;           // row (wr*16+r16)*128
    const int bB  = 16384 + wc * 2048 + r16 * 128;
    // fa[mt][ks] at aB + mt*8192 + (ks?sw1:sw0); fb[nt][ks] at bB + nt*4096 + ...

    f32x4 acc[2][4];
#pragma unroll
    for (int i = 0; i < 2; ++i)
#pragma unroll
        for (int jj = 0; jj < 4; ++jj)
            acc[i][jj] = (f32x4){0.f, 0.f, 0.f, 0.f};

    // K in ushorts: tile j -> +j*64; half-row offset (+64 rows) = 65536 ushorts.
#define STAGE_Aa(BUF, K) do { gld16(gA + (K),         lds + (BUF) + adst);         FENCE(); } while (0)
#define STAGE_Ab(BUF, K) do { gld16(gA + 65536 + (K), lds + (BUF) + 8192 + adst);  FENCE(); } while (0)
#define STAGE_B0(BUF, K) do { gld16(gB + (K),         lds + (BUF) + 16384 + adst); FENCE(); } while (0)
#define STAGE_B1(BUF, K) do { gld16(gB + 65536 + (K), lds + (BUF) + 24576 + adst); FENCE(); } while (0)

    // ---- prologue: tile0 (Aa,Ab,B0,B1) -> buf0; tile1 (Aa,Ab,B0) -> buf1 ----
    STAGE_Aa(0, 0);  STAGE_Ab(0, 0);  STAGE_B0(0, 0);  STAGE_B1(0, 0);
    STAGE_Aa(32768, 64);  STAGE_Ab(32768, 64);  STAGE_B0(32768, 64);
    asm volatile("s_waitcnt vmcnt(3)" ::: "memory");   // tile0 fully landed
    BARRIER();

#pragma unroll 2
    for (int j = 0; j < 16; ++j) {
        const int cur = (j & 1) * 32768;
        const int nxt = cur ^ 32768;
        const char* Lb = lds + cur;

        bf16x8 fa[2][2], fb[4][2];

        // ---------- phase 0: fa (all) + fb[0..1]; stage B1(j+1) -> nxt ----------
#pragma unroll
        for (int mt = 0; mt < 2; ++mt) {
            fa[mt][0] = *(const bf16x8*)(Lb + aB + mt * 8192 + sw0);
            fa[mt][1] = *(const bf16x8*)(Lb + aB + mt * 8192 + sw1);
        }
#pragma unroll
        for (int nt = 0; nt < 2; ++nt) {
            fb[nt][0] = *(const bf16x8*)(Lb + bB + nt * 4096 + sw0);
            fb[nt][1] = *(const bf16x8*)(Lb + bB + nt * 4096 + sw1);
        }
        if (j < 15) STAGE_B1(nxt, (j + 1) * 64);
        BARRIER();
        asm volatile("s_waitcnt lgkmcnt(0)" ::: "memory");
        __builtin_amdgcn_sched_barrier(0);                 // rule 18
        __builtin_amdgcn_s_setprio(1);
#pragma unroll
        for (int mt = 0; mt < 2; ++mt)
#pragma unroll
            for (int nt = 0; nt < 2; ++nt)
#pragma unroll
                for (int ks = 0; ks < 2; ++ks)
                    acc[mt][nt] = __builtin_amdgcn_mfma_f32_16x16x32_bf16(
                        fa[mt][ks], fb[nt][ks], acc[mt][nt], 0, 0, 0);
        __builtin_amdgcn_s_setprio(0);
        BARRIER();

        // ---------- phase 1: fb[2..3]; stage Aa,Ab,B0(j+2) -> cur; checkpoint ----------
#pragma unroll
        for (int nt = 2; nt < 4; ++nt) {
            fb[nt][0] = *(const bf16x8*)(Lb + bB + 8192 + (nt - 2) * 4096 + sw0);
            fb[nt][1] = *(const bf16x8*)(Lb + bB + 8192 + (nt - 2) * 4096 + sw1);
        }
        if (j < 14) {
            STAGE_Aa(cur, (j + 2) * 64);
            STAGE_Ab(cur, (j + 2) * 64);
            STAGE_B0(cur, (j + 2) * 64);
        }
        if (j < 14)       asm volatile("s_waitcnt vmcnt(3)" ::: "memory");
        else if (j == 14) asm volatile("s_waitcnt vmcnt(0)" ::: "memory");
        BARRIER();
        asm volatile("s_waitcnt lgkmcnt(0)" ::: "memory");
        __builtin_amdgcn_sched_barrier(0);
        __builtin_amdgcn_s_setprio(1);
#pragma unroll
        for (int mt = 0; mt < 2; ++mt)
#pragma unroll
            for (int nt = 2; nt < 4; ++nt)
#pragma unroll
                for (int ks = 0; ks < 2; ++ks)
                    acc[mt][nt] = __builtin_amdgcn_mfma_f32_16x16x32_bf16(
                        fa[mt][ks], fb[nt][ks], acc[mt][nt], 0, 0, 0);
        __builtin_amdgcn_s_setprio(0);
        BARRIER();
    }
#undef STAGE_Aa
#undef STAGE_Ab
#undef STAGE_B0
#undef STAGE_B1

    // ---- epilogue: frag (mt,nt) -> rows bm+(4mt+wr)*16+quad*4, cols bn+(2nt+wc)*16+r16 ----
    const int orow0 = bm + wr * 16 + quad * 4;
    const int ocol0 = bn + wc * 16 + r16;
#pragma unroll
    for (int nt = 0; nt < 4; ++nt) {
        const float bv = bias[ocol0 + nt * 32];
#pragma unroll
        for (int mt = 0; mt < 2; ++mt) {
            float* orow = out + (size_t)(orow0 + mt * 64) * 1024 + (ocol0 + nt * 32);
#pragma unroll
            for (int i = 0; i < 4; ++i)
                orow[(size_t)i * 1024] = acc[mt][nt][i] + bv;
        }
    }
}

// ---------------- fallback gemm (ws too small): old 128x128, fp32 A ----------------
template <bool XF32>
__global__ __launch_bounds__(256) void gemm_bt(
    const void* __restrict__ X_, const unsigned short* __restrict__ Wt,
    const float* __restrict__ bias, float* __restrict__ out)
{
    __shared__ __align__(16) unsigned short lA[128 * 32];
    __shared__ __align__(16) unsigned short lB[128 * 32];

    const int t    = threadIdx.x;
    const int lane = t & 63;
    const int w    = t >> 6;
    const int bm   = blockIdx.x * 128;
    const int bn   = blockIdx.y * 128;
    const int wm   = (w & 1) * 64;
    const int wn   = (w >> 1) * 64;
    const int r16  = lane & 15;
    const int quad = lane >> 4;

    const int srow = t >> 2;
    const int gc   = (t & 3) ^ ((srow >> 1) & 3);
    unsigned short* lsA = lA + t * 8;
    unsigned short* lsB = lB + t * 8;
    const size_t ga0 = (size_t)(bm + srow) * 1024 + gc * 8;
    const size_t ga1 = (size_t)(bm + srow + 64) * 1024 + gc * 8;
    const unsigned short* gB0 = Wt + (size_t)(bn + srow) * 1024 + gc * 8;

    const int p    = (quad ^ ((r16 >> 1) & 3)) * 8;
    const int aoff = (wm + r16) * 32 + p;
    const int boff = (wn + r16) * 32 + p;

    const unsigned short* Xb = (const unsigned short*)X_;
    const float*          Xf = (const float*)X_;

    f32x4 acc[4][4];
#pragma unroll
    for (int i = 0; i < 4; ++i)
#pragma unroll
        for (int j = 0; j < 4; ++j) {
            f32x4 z = {0.f, 0.f, 0.f, 0.f};
            acc[i][j] = z;
        }

    for (int kt = 0; kt < 1024; kt += 32) {
        if (XF32) {
            f32x4 a0 = *(const f32x4*)(Xf + ga0 + kt);
            f32x4 a1 = *(const f32x4*)(Xf + ga0 + kt + 4);
            f32x4 a2 = *(const f32x4*)(Xf + ga1 + kt);
            f32x4 a3 = *(const f32x4*)(Xf + ga1 + kt + 4);
            *(ushort8*)lsA          = cvt8u(a0, a1);
            *(ushort8*)(lsA + 2048) = cvt8u(a2, a3);
        } else {
            gld16(Xb + ga0 + kt, lsA);
            gld16(Xb + ga1 + kt, lsA + 2048);
        }
        gld16(gB0 + kt,             lsB);
        gld16(gB0 + kt + 64 * 1024, lsB + 2048);
        __syncthreads();

        bf16x8 fa[4], fb[4];
#pragma unroll
        for (int mt = 0; mt < 4; ++mt) fa[mt] = *(const bf16x8*)(lA + aoff + mt * 16 * 32);
#pragma unroll
        for (int nt = 0; nt < 4; ++nt) fb[nt] = *(const bf16x8*)(lB + boff + nt * 16 * 32);

#pragma unroll
        for (int mt = 0; mt < 4; ++mt)
#pragma unroll
            for (int nt = 0; nt < 4; ++nt)
                acc[mt][nt] = __builtin_amdgcn_mfma_f32_16x16x32_bf16(
                    fa[mt], fb[nt], acc[mt][nt], 0, 0, 0);

        __syncthreads();
    }

    const int orow0 = bm + wm + quad * 4;
    const int ocol0 = bn + wn + r16;
#pragma unroll
    for (int nt = 0; nt < 4; ++nt) {
        const float bv = bias[ocol0 + nt * 16];
#pragma unroll
        for (int mt = 0; mt < 4; ++mt)
#pragma unroll
            for (int i = 0; i < 4; ++i)
                out[(size_t)(orow0 + mt * 16 + i) * 1024 + (ocol0 + nt * 16)] =
                    acc[mt][nt][i] + bv;
    }
}

extern "C" void kernel_launch(void* const* d_in, const int* in_sizes, int n_in,
                              void* d_out, int out_size, void* d_ws, size_t ws_size,
                              hipStream_t stream) {
    const float* x  = (const float*)d_in[0];   // [M][1024]
    const float* W  = (const float*)d_in[1];   // [1024][1024]
    const float* b  = (const float*)d_in[2];   // [1024]
    const float* A  = (const float*)d_in[3];   // [16][1024]
    const float* Bm = (const float*)d_in[4];   // [1024][16]
    float* out = (float*)d_out;

    const int M = in_sizes[0] / 1024;          // 16384

    const bool fast = (ws_size >= ((size_t)(M)*1024*2 + (2u << 20) + 4096)) &&
                      (M % 128 == 0);
    if (fast) {
        unsigned short* xbf  = (unsigned short*)d_ws;
        unsigned short* Weff = xbf + (size_t)M * 1024;
        hipLaunchKernelGGL(prep, dim3(512 + M / 2), dim3(256), 0, stream,
                           x, W, A, Bm, xbf, Weff);
        hipLaunchKernelGGL(gemm256, dim3((M / 128) * 8), dim3(512), 65536, stream,
                           xbf, Weff, b, out);
    } else {
        unsigned short* Weff = (unsigned short*)d_ws;
        hipLaunchKernelGGL(prep, dim3(512), dim3(256), 0, stream,
                           x, W, A, Bm, (unsigned short*)nullptr, Weff);
        hipLaunchKernelGGL((gemm_bt<true>), dim3(M / 128, 8), dim3(256), 0, stream,
                           (const void*)x, Weff, b, out);
    }
}